// Round 2
// 451.711 us; speedup vs baseline: 1.0523x; 1.0523x over previous
//
#include <hip/hip_runtime.h>
#include <cstdint>
#include <cstddef>

#define B_   4096
#define T_   128
#define IN_  768
#define H_   256
#define BM_  256          // batch rows per workgroup (two 128-row x tiles)
#define KC1  (IN_ / 32)   // 24 k-chunks, layer 1
#define KC2  (H_ / 32)    // 8  k-chunks, layer 2

typedef __bf16 bf16_t;
typedef bf16_t bf16x8 __attribute__((ext_vector_type(8)));
typedef bf16_t bf16x4 __attribute__((ext_vector_type(4)));
typedef float  floatx16 __attribute__((ext_vector_type(16)));

#define MFMA32(a, b, c) __builtin_amdgcn_mfma_f32_32x32x16_bf16((a), (b), (c), 0, 0, 0)

// Counted-vmcnt barriers (T3/T4): never drain vmcnt to 0 in the steady-state
// loops; prefetched global_load_lds stay in flight ACROSS barriers.
// lgkmcnt(0) before the barrier orders own ds_writes (epilogue handoff).
#define WAITBAR(N) asm volatile("s_waitcnt vmcnt(" #N ") lgkmcnt(0)\n\ts_barrier" ::: "memory")
#define BAR_ONLY() asm volatile("s_barrier" ::: "memory")
#define WAIT_LGK_BAR() asm volatile("s_waitcnt lgkmcnt(0)\n\ts_barrier" ::: "memory")

__device__ __forceinline__ void gl_lds16(const bf16_t* g, bf16_t* l) {
    __builtin_amdgcn_global_load_lds(
        (const __attribute__((address_space(1))) void*)g,
        (__attribute__((address_space(3))) void*)l, 16, 0, 0);
}

// ---------- W [t][K][H] fp32 -> A-frag tiles [t][kc][kq=4][h=256][8k] bf16 ----------
// One block per (t,kc) 32k x 256h tile. float4 reads, 64B-contiguous writes per thread.
__global__ __launch_bounds__(256)
void tile_w2(const float* __restrict__ src, bf16_t* __restrict__ dst, int K, int KC) {
    const int t  = blockIdx.x / KC;
    const int kc = blockIdx.x - t * KC;
    const int kq = threadIdx.x >> 6;           // 0..3
    const int h4 = (threadIdx.x & 63) * 4;     // 0..252
    const float* s = src + ((size_t)t * K + kc * 32 + kq * 8) * H_ + h4;
    float r[8][4];
#pragma unroll
    for (int e = 0; e < 8; ++e) {
        float4 v = *(const float4*)(s + (size_t)e * H_);
        r[e][0] = v.x; r[e][1] = v.y; r[e][2] = v.z; r[e][3] = v.w;
    }
    bf16_t* d = dst + (((size_t)(t * KC + kc) * 4 + kq) * H_ + h4) * 8;
#pragma unroll
    for (int c = 0; c < 4; ++c) {
        bf16x8 v;
#pragma unroll
        for (int e = 0; e < 8; ++e) v[e] = (bf16_t)r[e][c];
        *(bf16x8*)(d + c * 8) = v;
    }
}

// ---------- x [B][IN] fp32 -> B-frag tiles [mblk][kc][kq=4][m=128][8k] bf16 ----------
__global__ void tile_x_kernel(const float* __restrict__ src, bf16_t* __restrict__ dst,
                              long long total8) {
    long long o = (long long)blockIdx.x * blockDim.x + threadIdx.x;
    if (o >= total8) return;
    int m = (int)(o & 127);
    long long q = o >> 7;
    int kq = (int)(q & 3);
    int q2 = (int)(q >> 2);
    int kc   = q2 % KC1;
    int mblk = q2 / KC1;
    const float* s = src + ((long long)mblk * 128 + m) * IN_ + kc * 32 + kq * 8;
    float4 a = *(const float4*)s;
    float4 b = *(const float4*)(s + 4);
    bf16x8 v;
    v[0] = (bf16_t)a.x; v[1] = (bf16_t)a.y; v[2] = (bf16_t)a.z; v[3] = (bf16_t)a.w;
    v[4] = (bf16_t)b.x; v[5] = (bf16_t)b.y; v[6] = (bf16_t)b.z; v[7] = (bf16_t)b.w;
    *(bf16x8*)(dst + o * 8) = v;
}

// ---------- fused per-task MLP, mega-WG: 512 threads, 256 batch rows, 1 WG/CU.
// Sync restructure vs prior version: layer-1 uses a ring-4 chunk buffer (4 x 32KB
// inside hbuf, which is dead until epilogue-1) with prefetch distance 3 and ONE
// raw s_barrier per chunk guarded by s_waitcnt vmcnt(8) — staging loads get ~3
// comp-phases to land and are never drained to 0 (T3/T4). Layer-2 wt2 is
// double-buffered (vmcnt(2) per chunk); W2 chunks 0/1 are issued in the layer-1
// tail and land under epilogue-1. LDS = 128K hbuf + 32K wt2 = 160 KB (1 WG/CU).
// hbuf layout [blk=h/8][m=256][8h] bf16: epilogue b64 stores, layer2 B-frag b128
// reads, and layer3 reads are all lane-contiguous (no bank conflicts). ----------
__global__ __launch_bounds__(512, 2)
void mtmlp_fused3(const bf16_t* __restrict__ xt, const bf16_t* __restrict__ w1t,
                  const float* __restrict__ b1, const bf16_t* __restrict__ w2t,
                  const float* __restrict__ b2, const float* __restrict__ W3,
                  const float* __restrict__ b3, float* __restrict__ out) {
    // XCD-locality swizzle: hardware maps consecutive workgroup ids round-robin
    // across 8 XCDs. Decode so XCD k owns tasks [16k,16k+16): W1[t]/W2[t] stay
    // L2-resident per XCD; the 2 co-running t's share x through L2 too.
    const int L    = blockIdx.x;          // 0..2047
    const int xcd  = L & 7;
    const int slot = L >> 3;              // 0..255
    const int t    = xcd * 16 + (slot >> 4);
    const int mblk = slot & 15;
    const int m0   = mblk * BM_;
    const int mb0  = mblk * 2;            // 128-row tile index

    const int tid  = threadIdx.x;
    const int lane = tid & 63;
    const int wid  = tid >> 6;            // 0..7
    const int wm   = wid >> 2;            // 0..1 : h half (128)
    const int wn   = wid & 3;             // 0..3 : m quarter (64)
    const int ln31 = lane & 31;
    const int hi   = lane >> 5;

    __shared__ __align__(16) bf16_t hbuf[BM_ * H_];       // 128 KB: L1 ring-4, then h1/h2
    __shared__ __align__(16) bf16_t wt2[2 * 4 * H_ * 8];  // 32 KB: L2 ring-2; w3s alias
    float* w3s = (float*)wt2;

    floatx16 acc[4][2];
#pragma unroll
    for (int i = 0; i < 4; ++i)
#pragma unroll
        for (int j = 0; j < 2; ++j)
#pragma unroll
            for (int e = 0; e < 16; ++e) acc[i][j][e] = 0.0f;

    // ---------------- layer 1: h1^T = W1^T · x^T ----------------
    const bf16_t* w1base = w1t + (size_t)t * KC1 * 8192;
    const bf16_t* w2base = w2t + (size_t)t * KC2 * 8192;
    const bf16_t* x0base = xt + (size_t)mb0 * KC1 * 4096;
    const bf16_t* x1base = xt + (size_t)(mb0 + 1) * KC1 * 4096;

    auto stage1 = [&](bf16_t* buf, int kc) {               // 4 vmcnt ops
        const bf16_t* ws = w1base + (size_t)kc * 8192;
        gl_lds16(ws + tid * 8,        buf + tid * 8);
        gl_lds16(ws + 4096 + tid * 8, buf + 4096 + tid * 8);
        gl_lds16(x0base + (size_t)kc * 4096 + tid * 8, buf + 8192 + tid * 8);
        gl_lds16(x1base + (size_t)kc * 4096 + tid * 8, buf + 12288 + tid * 8);
    };
    auto stage2 = [&](bf16_t* dstb, int kc) {              // 2 vmcnt ops
        const bf16_t* ws = w2base + (size_t)kc * 8192;
        gl_lds16(ws + tid * 8,        dstb + tid * 8);
        gl_lds16(ws + 4096 + tid * 8, dstb + 4096 + tid * 8);
    };
    auto comp1 = [&](const bf16_t* buf) {
#pragma unroll
        for (int s = 0; s < 2; ++s) {
            const int kq = s * 2 + hi;
            bf16x8 A[4], Bf[2];
#pragma unroll
            for (int i = 0; i < 4; ++i)
                A[i] = *(const bf16x8*)(buf + (size_t)(kq * H_ + wm * 128 + i * 32 + ln31) * 8);
#pragma unroll
            for (int j = 0; j < 2; ++j) {
                const int mm = wn * 64 + j * 32 + ln31;
                Bf[j] = *(const bf16x8*)(buf + 8192 + (mm >> 7) * 4096 +
                                         (size_t)(kq * 128 + (mm & 127)) * 8);
            }
#pragma unroll
            for (int i = 0; i < 4; ++i)
#pragma unroll
                for (int j = 0; j < 2; ++j) acc[i][j] = MFMA32(A[i], Bf[j], acc[i][j]);
        }
    };

    // Prologue: stage chunks 0..2 (12 loads in flight).
    stage1(hbuf,          0);
    stage1(hbuf + 16384,  1);
    stage1(hbuf + 32768,  2);

    // Main loop, chunks 0..19: wait own chunk (12 outstanding -> 8), barrier,
    // restage distance-3, compute. Buffer index kc&3 is static per unrolled j.
    for (int kc4 = 0; kc4 < 5; ++kc4) {
        const int kc = kc4 * 4;
#pragma unroll
        for (int j = 0; j < 4; ++j) {
            WAITBAR(8);
            stage1(hbuf + ((j + 3) & 3) * 16384, kc + j + 3);   // chunk <= 22
            comp1(hbuf + j * 16384);
        }
    }
    // Tail: kc = 20..23. W2 chunks 0/1 are issued here so their latency hides
    // under the remaining comps + epilogue-1.
    WAITBAR(8); stage1(hbuf + 49152, 23); comp1(hbuf);            // kc=20
    WAITBAR(8); stage2(wt2, 0);           comp1(hbuf + 16384);    // kc=21
    WAITBAR(6); stage2(wt2 + 8192, 1);    comp1(hbuf + 32768);    // kc=22 (c22 done, c23+s2_0 out)
    WAITBAR(4);                           comp1(hbuf + 49152);    // kc=23 (c23 done, s2_0+s2_1 out)

    BAR_ONLY();   // all ring reads done before epilogue overwrites hbuf

    // epilogue 1: bias + relu -> hbuf [blk][m][8]
#pragma unroll
    for (int i = 0; i < 4; ++i) {
#pragma unroll
        for (int g = 0; g < 4; ++g) {
            const int h0 = wm * 128 + i * 32 + g * 8 + 4 * hi;
            float4 bias = *(const float4*)(b1 + t * H_ + h0);
            const int blk = h0 >> 3;
#pragma unroll
            for (int j = 0; j < 2; ++j) {
                const int mm = wn * 64 + j * 32 + ln31;
                bf16x4 o;
                o[0] = (bf16_t)fmaxf(acc[i][j][4 * g + 0] + bias.x, 0.0f);
                o[1] = (bf16_t)fmaxf(acc[i][j][4 * g + 1] + bias.y, 0.0f);
                o[2] = (bf16_t)fmaxf(acc[i][j][4 * g + 2] + bias.z, 0.0f);
                o[3] = (bf16_t)fmaxf(acc[i][j][4 * g + 3] + bias.w, 0.0f);
                *(bf16x4*)(hbuf + (size_t)(blk * BM_ + mm) * 8 + 4 * hi) = o;
            }
        }
    }

#pragma unroll
    for (int i = 0; i < 4; ++i)
#pragma unroll
        for (int j = 0; j < 2; ++j)
#pragma unroll
            for (int e = 0; e < 16; ++e) acc[i][j][e] = 0.0f;

    // ---------------- layer 2: h2^T = W2^T · h1^T (ring-2 wt2) ----------------
    auto comp2 = [&](const bf16_t* wbuf, int kc) {
#pragma unroll
        for (int s = 0; s < 2; ++s) {
            const int kq = s * 2 + hi;
            bf16x8 A[4], Bf[2];
#pragma unroll
            for (int i = 0; i < 4; ++i)
                A[i] = *(const bf16x8*)(wbuf + (size_t)(kq * H_ + wm * 128 + i * 32 + ln31) * 8);
            const int blk = kc * 4 + kq;
#pragma unroll
            for (int j = 0; j < 2; ++j) {
                const int mm = wn * 64 + j * 32 + ln31;
                Bf[j] = *(const bf16x8*)(hbuf + (size_t)(blk * BM_ + mm) * 8);
            }
#pragma unroll
            for (int i = 0; i < 4; ++i)
#pragma unroll
                for (int j = 0; j < 2; ++j) acc[i][j] = MFMA32(A[i], Bf[j], acc[i][j]);
        }
    };

#pragma unroll
    for (int kc = 0; kc < KC2; ++kc) {
        // Entering: chunks {kc, kc+1} in flight (4 loads) except last (2).
        if (kc < KC2 - 1) { WAITBAR(2); } else { WAITBAR(0); }
        comp2(wt2 + (kc & 1) * 8192, kc);
        BAR_ONLY();                                   // readers done before restage
        if (kc < KC2 - 2) stage2(wt2 + (kc & 1) * 8192, kc + 2);
    }

    // epilogue 2: bias + relu -> h2 (hbuf, same layout); stage W3 into w3s
    if (tid < H_) w3s[tid] = W3[t * H_ + tid];
#pragma unroll
    for (int i = 0; i < 4; ++i) {
#pragma unroll
        for (int g = 0; g < 4; ++g) {
            const int h0 = wm * 128 + i * 32 + g * 8 + 4 * hi;
            float4 bias = *(const float4*)(b2 + t * H_ + h0);
            const int blk = h0 >> 3;
#pragma unroll
            for (int j = 0; j < 2; ++j) {
                const int mm = wn * 64 + j * 32 + ln31;
                bf16x4 o;
                o[0] = (bf16_t)fmaxf(acc[i][j][4 * g + 0] + bias.x, 0.0f);
                o[1] = (bf16_t)fmaxf(acc[i][j][4 * g + 1] + bias.y, 0.0f);
                o[2] = (bf16_t)fmaxf(acc[i][j][4 * g + 2] + bias.z, 0.0f);
                o[3] = (bf16_t)fmaxf(acc[i][j][4 * g + 3] + bias.w, 0.0f);
                *(bf16x4*)(hbuf + (size_t)(blk * BM_ + mm) * 8 + 4 * hi) = o;
            }
        }
    }
    WAIT_LGK_BAR();   // own ds_writes drained, then barrier: h2 + w3s visible

    // ---------------- layer 3: out[m,t] = h2[m,:]·W3[t,:] + b3[t] ----------------
    {
        const int m = tid >> 1, seg = tid & 1;   // 2 threads/row, 128 h each
        float sum = 0.0f;
#pragma unroll
        for (int b = 0; b < 16; ++b) {
            const int blk = seg * 16 + b;
            const bf16x8 v = *(const bf16x8*)(hbuf + (size_t)(blk * BM_ + m) * 8);
            const float* w = w3s + blk * 8;
#pragma unroll
            for (int e = 0; e < 8; ++e) sum += (float)v[e] * w[e];
        }
        sum += __shfl_xor(sum, 1);
        if (seg == 0) out[(size_t)(m0 + m) * T_ + t] = sum + b3[t];
    }
}

extern "C" void kernel_launch(void* const* d_in, const int* in_sizes, int n_in,
                              void* d_out, int out_size, void* d_ws, size_t ws_size,
                              hipStream_t stream) {
    const float* x  = (const float*)d_in[0];
    const float* W1 = (const float*)d_in[1];
    const float* b1 = (const float*)d_in[2];
    const float* W2 = (const float*)d_in[3];
    const float* b2 = (const float*)d_in[4];
    const float* W3 = (const float*)d_in[5];
    const float* b3 = (const float*)d_in[6];
    float* out = (float*)d_out;

    const size_t nx  = (size_t)B_ * IN_;        // 3,145,728
    const size_t nw1 = (size_t)T_ * IN_ * H_;   // 25,165,824
    const size_t nw2 = (size_t)T_ * H_ * H_;    // 8,388,608

    bf16_t* xt  = (bf16_t*)d_ws;
    bf16_t* w1t = xt + nx;
    bf16_t* w2t = w1t + nw1;

    tile_x_kernel<<<dim3((unsigned)(nx / 8 / 256)), 256, 0, stream>>>(x, xt, (long long)(nx / 8));
    tile_w2<<<dim3(T_ * KC1), 256, 0, stream>>>(W1, w1t, IN_, KC1);
    tile_w2<<<dim3(T_ * KC2), 256, 0, stream>>>(W2, w2t, H_, KC2);

    mtmlp_fused3<<<dim3(2048), 512, 0, stream>>>(xt, w1t, b1, w2t, b2, W3, b3, out);
}